// Round 1
// baseline (365.714 us; speedup 1.0000x reference)
//
#include <hip/hip_runtime.h>

// ws layout (bytes):
//   0: double sum_sq
//   8: double sum_abs
//  16: double masked_sum_sq
//  24: double masked_sum_abs
//  32: unsigned long long cnt_sq
//  40: unsigned long long cnt_abs
//  48: float mse
//  52: float mae

#define THREADS 256
#define BLOCKS 2048

__device__ __forceinline__ float wave_reduce_f(float v) {
    for (int o = 32; o > 0; o >>= 1) v += __shfl_down(v, o);
    return v;
}
__device__ __forceinline__ unsigned wave_reduce_u(unsigned v) {
    for (int o = 32; o > 0; o >>= 1) v += __shfl_down(v, o);
    return v;
}

__global__ void pass1_sums(const float4* __restrict__ a, const float4* __restrict__ b,
                           int n4, int n, double* __restrict__ wsd) {
    float ssq = 0.f, sab = 0.f;
    const int stride = gridDim.x * blockDim.x;
    for (int i = blockIdx.x * blockDim.x + threadIdx.x; i < n4; i += stride) {
        float4 x = a[i], y = b[i];
        float d0 = x.x - y.x, d1 = x.y - y.y, d2 = x.z - y.z, d3 = x.w - y.w;
        ssq += d0 * d0 + d1 * d1 + d2 * d2 + d3 * d3;
        sab += fabsf(d0) + fabsf(d1) + fabsf(d2) + fabsf(d3);
    }
    // scalar tail (n not multiple of 4)
    const float* as = (const float*)a;
    const float* bs = (const float*)b;
    for (int i = n4 * 4 + blockIdx.x * blockDim.x + threadIdx.x; i < n; i += stride) {
        float d = as[i] - bs[i];
        ssq += d * d;
        sab += fabsf(d);
    }

    ssq = wave_reduce_f(ssq);
    sab = wave_reduce_f(sab);

    __shared__ float s1[THREADS / 64], s2[THREADS / 64];
    int lane = threadIdx.x & 63, wave = threadIdx.x >> 6;
    if (lane == 0) { s1[wave] = ssq; s2[wave] = sab; }
    __syncthreads();
    if (threadIdx.x == 0) {
        float t1 = 0.f, t2 = 0.f;
        for (int w = 0; w < THREADS / 64; ++w) { t1 += s1[w]; t2 += s2[w]; }
        atomicAdd(&wsd[0], (double)t1);
        atomicAdd(&wsd[1], (double)t2);
    }
}

__global__ void finalize_means(double* __restrict__ wsd, float* __restrict__ wsf, double inv_n) {
    if (threadIdx.x == 0) {
        wsf[0] = (float)(wsd[0] * inv_n);  // mse_loss
        wsf[1] = (float)(wsd[1] * inv_n);  // mae_loss
    }
}

__global__ void pass2_masked(const float4* __restrict__ a, const float4* __restrict__ b,
                             int n4, int n,
                             double* __restrict__ wsd, unsigned long long* __restrict__ wsu,
                             const float* __restrict__ wsf) {
    const float mse = wsf[0];
    const float mae = wsf[1];
    float mssq = 0.f, msab = 0.f;
    unsigned c1 = 0, c2 = 0;
    const int stride = gridDim.x * blockDim.x;
    for (int i = blockIdx.x * blockDim.x + threadIdx.x; i < n4; i += stride) {
        float4 x = a[i], y = b[i];
        float d[4] = {x.x - y.x, x.y - y.y, x.z - y.z, x.w - y.w};
#pragma unroll
        for (int k = 0; k < 4; ++k) {
            float dsq = d[k] * d[k];
            float ad = fabsf(d[k]);
            if (dsq >= mse) { mssq += dsq; c1++; }
            if (ad >= mae)  { msab += ad;  c2++; }
        }
    }
    const float* as = (const float*)a;
    const float* bs = (const float*)b;
    for (int i = n4 * 4 + blockIdx.x * blockDim.x + threadIdx.x; i < n; i += stride) {
        float d = as[i] - bs[i];
        float dsq = d * d;
        float ad = fabsf(d);
        if (dsq >= mse) { mssq += dsq; c1++; }
        if (ad >= mae)  { msab += ad;  c2++; }
    }

    mssq = wave_reduce_f(mssq);
    msab = wave_reduce_f(msab);
    c1 = wave_reduce_u(c1);
    c2 = wave_reduce_u(c2);

    __shared__ float s1[THREADS / 64], s2[THREADS / 64];
    __shared__ unsigned u1[THREADS / 64], u2[THREADS / 64];
    int lane = threadIdx.x & 63, wave = threadIdx.x >> 6;
    if (lane == 0) { s1[wave] = mssq; s2[wave] = msab; u1[wave] = c1; u2[wave] = c2; }
    __syncthreads();
    if (threadIdx.x == 0) {
        float t1 = 0.f, t2 = 0.f;
        unsigned long long k1 = 0, k2 = 0;
        for (int w = 0; w < THREADS / 64; ++w) { t1 += s1[w]; t2 += s2[w]; k1 += u1[w]; k2 += u2[w]; }
        atomicAdd(&wsd[2], (double)t1);
        atomicAdd(&wsd[3], (double)t2);
        atomicAdd(&wsu[0], k1);
        atomicAdd(&wsu[1], k2);
    }
}

__global__ void finalize_loss(const double* __restrict__ wsd,
                              const unsigned long long* __restrict__ wsu,
                              const float* __restrict__ wsf, float* __restrict__ out) {
    if (threadIdx.x == 0) {
        double mse_thr = wsu[0] ? wsd[2] / (double)wsu[0] : 0.0;
        double mae_thr = wsu[1] ? wsd[3] / (double)wsu[1] : 0.0;
        double comb_thr = 0.5 * mae_thr + 0.5 * mse_thr;
        double comb_non = 0.5 * (double)wsf[1] + 0.5 * (double)wsf[0];
        out[0] = (float)(0.5 * comb_thr + 0.5 * comb_non);
    }
}

extern "C" void kernel_launch(void* const* d_in, const int* in_sizes, int n_in,
                              void* d_out, int out_size, void* d_ws, size_t ws_size,
                              hipStream_t stream) {
    const float* a = (const float*)d_in[0];
    const float* b = (const float*)d_in[1];
    const int n = in_sizes[0];
    const int n4 = n / 4;

    double* wsd = (double*)d_ws;
    unsigned long long* wsu = (unsigned long long*)((char*)d_ws + 32);
    float* wsf = (float*)((char*)d_ws + 48);

    hipMemsetAsync(d_ws, 0, 64, stream);

    pass1_sums<<<BLOCKS, THREADS, 0, stream>>>((const float4*)a, (const float4*)b, n4, n, wsd);
    finalize_means<<<1, 64, 0, stream>>>(wsd, wsf, 1.0 / (double)n);
    pass2_masked<<<BLOCKS, THREADS, 0, stream>>>((const float4*)a, (const float4*)b, n4, n,
                                                 wsd, wsu, wsf);
    finalize_loss<<<1, 64, 0, stream>>>(wsd, wsu, wsf, (float*)d_out);
}

// Round 2
// 250.925 us; speedup vs baseline: 1.4575x; 1.4575x over previous
//
#include <hip/hip_runtime.h>

// ws layout (floats/uints, per-block partials — NO atomics, no memset needed):
//   off 0     : float p1sq[NB]
//   off 8192  : float p1ab[NB]
//   off 16384 : float p2sq[NB]
//   off 24576 : float p2ab[NB]
//   off 32768 : uint  p2c1[NB]
//   off 40960 : uint  p2c2[NB]
//   off 49152 : float means[2]   (mse, mae)

#define THREADS 256
#define NB 2048
#define UNROLL 4

__device__ __forceinline__ float wave_reduce_f(float v) {
    for (int o = 32; o > 0; o >>= 1) v += __shfl_down(v, o);
    return v;
}
__device__ __forceinline__ unsigned wave_reduce_u(unsigned v) {
    for (int o = 32; o > 0; o >>= 1) v += __shfl_down(v, o);
    return v;
}
__device__ __forceinline__ double wave_reduce_d(double v) {
    for (int o = 32; o > 0; o >>= 1) v += __shfl_down(v, o);
    return v;
}

__global__ void pass1_sums(const float4* __restrict__ a, const float4* __restrict__ b,
                           int n4, int n, float* __restrict__ psq, float* __restrict__ pab) {
    float ssq = 0.f, sab = 0.f;
    const int tile_total = gridDim.x * blockDim.x * UNROLL;
    const int n4_main = (n4 / tile_total) * tile_total;

    for (int base = (blockIdx.x * blockDim.x) * UNROLL + threadIdx.x;
         base < n4_main; base += tile_total) {
        float4 xa[UNROLL], xb[UNROLL];
#pragma unroll
        for (int j = 0; j < UNROLL; ++j) {
            xa[j] = a[base + j * THREADS];
            xb[j] = b[base + j * THREADS];
        }
#pragma unroll
        for (int j = 0; j < UNROLL; ++j) {
            float d0 = xa[j].x - xb[j].x, d1 = xa[j].y - xb[j].y;
            float d2 = xa[j].z - xb[j].z, d3 = xa[j].w - xb[j].w;
            ssq += d0 * d0 + d1 * d1 + d2 * d2 + d3 * d3;
            sab += fabsf(d0) + fabsf(d1) + fabsf(d2) + fabsf(d3);
        }
    }
    // remainder float4s
    for (int i = n4_main + blockIdx.x * blockDim.x + threadIdx.x; i < n4;
         i += gridDim.x * blockDim.x) {
        float4 x = a[i], y = b[i];
        float d0 = x.x - y.x, d1 = x.y - y.y, d2 = x.z - y.z, d3 = x.w - y.w;
        ssq += d0 * d0 + d1 * d1 + d2 * d2 + d3 * d3;
        sab += fabsf(d0) + fabsf(d1) + fabsf(d2) + fabsf(d3);
    }
    // scalar tail
    const float* as = (const float*)a;
    const float* bs = (const float*)b;
    for (int i = n4 * 4 + blockIdx.x * blockDim.x + threadIdx.x; i < n;
         i += gridDim.x * blockDim.x) {
        float d = as[i] - bs[i];
        ssq += d * d;
        sab += fabsf(d);
    }

    ssq = wave_reduce_f(ssq);
    sab = wave_reduce_f(sab);
    __shared__ float s1[THREADS / 64], s2[THREADS / 64];
    int lane = threadIdx.x & 63, wave = threadIdx.x >> 6;
    if (lane == 0) { s1[wave] = ssq; s2[wave] = sab; }
    __syncthreads();
    if (threadIdx.x == 0) {
        float t1 = 0.f, t2 = 0.f;
        for (int w = 0; w < THREADS / 64; ++w) { t1 += s1[w]; t2 += s2[w]; }
        psq[blockIdx.x] = t1;
        pab[blockIdx.x] = t2;
    }
}

__global__ void finalize_means(const float* __restrict__ psq, const float* __restrict__ pab,
                               float* __restrict__ means, int nb, double inv_n) {
    double s1 = 0.0, s2 = 0.0;
    for (int i = threadIdx.x; i < nb; i += blockDim.x) { s1 += psq[i]; s2 += pab[i]; }
    s1 = wave_reduce_d(s1);
    s2 = wave_reduce_d(s2);
    __shared__ double w1[THREADS / 64], w2[THREADS / 64];
    int lane = threadIdx.x & 63, wave = threadIdx.x >> 6;
    if (lane == 0) { w1[wave] = s1; w2[wave] = s2; }
    __syncthreads();
    if (threadIdx.x == 0) {
        double t1 = 0.0, t2 = 0.0;
        for (int w = 0; w < THREADS / 64; ++w) { t1 += w1[w]; t2 += w2[w]; }
        means[0] = (float)(t1 * inv_n);  // mse
        means[1] = (float)(t2 * inv_n);  // mae
    }
}

__global__ void pass2_masked(const float4* __restrict__ a, const float4* __restrict__ b,
                             int n4, int n, const float* __restrict__ means,
                             float* __restrict__ p2sq, float* __restrict__ p2ab,
                             unsigned* __restrict__ p2c1, unsigned* __restrict__ p2c2) {
    const float mse = means[0];
    const float mae = means[1];
    float mssq = 0.f, msab = 0.f;
    unsigned c1 = 0, c2 = 0;
    const int tile_total = gridDim.x * blockDim.x * UNROLL;
    const int n4_main = (n4 / tile_total) * tile_total;

    for (int base = (blockIdx.x * blockDim.x) * UNROLL + threadIdx.x;
         base < n4_main; base += tile_total) {
        float4 xa[UNROLL], xb[UNROLL];
#pragma unroll
        for (int j = 0; j < UNROLL; ++j) {
            xa[j] = a[base + j * THREADS];
            xb[j] = b[base + j * THREADS];
        }
#pragma unroll
        for (int j = 0; j < UNROLL; ++j) {
            float d[4] = {xa[j].x - xb[j].x, xa[j].y - xb[j].y,
                          xa[j].z - xb[j].z, xa[j].w - xb[j].w};
#pragma unroll
            for (int k = 0; k < 4; ++k) {
                float dsq = d[k] * d[k];
                float ad = fabsf(d[k]);
                if (dsq >= mse) { mssq += dsq; c1++; }
                if (ad >= mae)  { msab += ad;  c2++; }
            }
        }
    }
    for (int i = n4_main + blockIdx.x * blockDim.x + threadIdx.x; i < n4;
         i += gridDim.x * blockDim.x) {
        float4 x = a[i], y = b[i];
        float d[4] = {x.x - y.x, x.y - y.y, x.z - y.z, x.w - y.w};
#pragma unroll
        for (int k = 0; k < 4; ++k) {
            float dsq = d[k] * d[k];
            float ad = fabsf(d[k]);
            if (dsq >= mse) { mssq += dsq; c1++; }
            if (ad >= mae)  { msab += ad;  c2++; }
        }
    }
    const float* as = (const float*)a;
    const float* bs = (const float*)b;
    for (int i = n4 * 4 + blockIdx.x * blockDim.x + threadIdx.x; i < n;
         i += gridDim.x * blockDim.x) {
        float d = as[i] - bs[i];
        float dsq = d * d;
        float ad = fabsf(d);
        if (dsq >= mse) { mssq += dsq; c1++; }
        if (ad >= mae)  { msab += ad;  c2++; }
    }

    mssq = wave_reduce_f(mssq);
    msab = wave_reduce_f(msab);
    c1 = wave_reduce_u(c1);
    c2 = wave_reduce_u(c2);
    __shared__ float s1[THREADS / 64], s2[THREADS / 64];
    __shared__ unsigned u1[THREADS / 64], u2[THREADS / 64];
    int lane = threadIdx.x & 63, wave = threadIdx.x >> 6;
    if (lane == 0) { s1[wave] = mssq; s2[wave] = msab; u1[wave] = c1; u2[wave] = c2; }
    __syncthreads();
    if (threadIdx.x == 0) {
        float t1 = 0.f, t2 = 0.f;
        unsigned k1 = 0, k2 = 0;
        for (int w = 0; w < THREADS / 64; ++w) { t1 += s1[w]; t2 += s2[w]; k1 += u1[w]; k2 += u2[w]; }
        p2sq[blockIdx.x] = t1;
        p2ab[blockIdx.x] = t2;
        p2c1[blockIdx.x] = k1;
        p2c2[blockIdx.x] = k2;
    }
}

__global__ void finalize_loss(const float* __restrict__ p2sq, const float* __restrict__ p2ab,
                              const unsigned* __restrict__ p2c1, const unsigned* __restrict__ p2c2,
                              const float* __restrict__ means, int nb, float* __restrict__ out) {
    double s1 = 0.0, s2 = 0.0;
    unsigned long long k1 = 0, k2 = 0;
    for (int i = threadIdx.x; i < nb; i += blockDim.x) {
        s1 += p2sq[i]; s2 += p2ab[i]; k1 += p2c1[i]; k2 += p2c2[i];
    }
    s1 = wave_reduce_d(s1);
    s2 = wave_reduce_d(s2);
    for (int o = 32; o > 0; o >>= 1) k1 += __shfl_down(k1, o);
    for (int o = 32; o > 0; o >>= 1) k2 += __shfl_down(k2, o);
    __shared__ double w1[THREADS / 64], w2[THREADS / 64];
    __shared__ unsigned long long v1[THREADS / 64], v2[THREADS / 64];
    int lane = threadIdx.x & 63, wave = threadIdx.x >> 6;
    if (lane == 0) { w1[wave] = s1; w2[wave] = s2; v1[wave] = k1; v2[wave] = k2; }
    __syncthreads();
    if (threadIdx.x == 0) {
        double t1 = 0.0, t2 = 0.0;
        unsigned long long c1 = 0, c2 = 0;
        for (int w = 0; w < THREADS / 64; ++w) { t1 += w1[w]; t2 += w2[w]; c1 += v1[w]; c2 += v2[w]; }
        double mse_thr = c1 ? t1 / (double)c1 : 0.0;
        double mae_thr = c2 ? t2 / (double)c2 : 0.0;
        double comb_thr = 0.5 * mae_thr + 0.5 * mse_thr;
        double comb_non = 0.5 * (double)means[1] + 0.5 * (double)means[0];
        out[0] = (float)(0.5 * comb_thr + 0.5 * comb_non);
    }
}

extern "C" void kernel_launch(void* const* d_in, const int* in_sizes, int n_in,
                              void* d_out, int out_size, void* d_ws, size_t ws_size,
                              hipStream_t stream) {
    const float* a = (const float*)d_in[0];
    const float* b = (const float*)d_in[1];
    const int n = in_sizes[0];
    const int n4 = n / 4;

    char* ws = (char*)d_ws;
    float* p1sq = (float*)(ws + 0);
    float* p1ab = (float*)(ws + 8192);
    float* p2sq = (float*)(ws + 16384);
    float* p2ab = (float*)(ws + 24576);
    unsigned* p2c1 = (unsigned*)(ws + 32768);
    unsigned* p2c2 = (unsigned*)(ws + 40960);
    float* means = (float*)(ws + 49152);

    pass1_sums<<<NB, THREADS, 0, stream>>>((const float4*)a, (const float4*)b, n4, n, p1sq, p1ab);
    finalize_means<<<1, THREADS, 0, stream>>>(p1sq, p1ab, means, NB, 1.0 / (double)n);
    pass2_masked<<<NB, THREADS, 0, stream>>>((const float4*)a, (const float4*)b, n4, n, means,
                                             p2sq, p2ab, p2c1, p2c2);
    finalize_loss<<<1, THREADS, 0, stream>>>(p2sq, p2ab, p2c1, p2c2, means, NB, (float*)d_out);
}